// Round 17
// baseline (400.037 us; speedup 1.0000x reference)
//
#include <hip/hip_runtime.h>
#include <cstdint>

typedef unsigned short u16;
typedef u16 u16x8 __attribute__((ext_vector_type(8)));
typedef __bf16 bf16x8 __attribute__((ext_vector_type(8)));
typedef float f32x4 __attribute__((ext_vector_type(4)));

#define DEV static __device__ __forceinline__

// problem constants
constexpr int NT = 8192;         // tokens
constexpr int NP = NT * 2;       // 16384 (token, k) pairs
constexpr int NE = 8;
constexpr int DM = 1024;
constexpr int DF = 2048;
constexpr int MAXS = 17664;      // 16384 + 8*127 pad + 256-tile overhang
constexpr int MAXT128 = 136;
constexpr int NWG1 = 8 * 142;    // 1136: xcd n-major mapping (R11 best)
constexpr int NWG2 = 8 * MAXT128;// 1088
constexpr int NTRANS = 24 * 512; // transpose sub-grid (flattened)
constexpr int NPREP = MAXS + NTRANS;

DEV u16 f2bf(float f) {          // RTNE float -> bf16 bits
  uint32_t u = __builtin_bit_cast(uint32_t, f);
  u += 0x7fffu + ((u >> 16) & 1u);
  return (u16)(u >> 16);
}

DEV float bflo(uint32_t u) { return __builtin_bit_cast(float, u << 16); }
DEV float bfhi(uint32_t u) { return __builtin_bit_cast(float, u & 0xffff0000u); }

DEV void gload16(const void* g, void* l) {
  __builtin_amdgcn_global_load_lds((const __attribute__((address_space(1))) void*)g,
                                   (__attribute__((address_space(3))) void*)l, 16, 0, 0);
}

DEV bf16x8 ldfrag(const char* p) { return __builtin_bit_cast(bf16x8, *(const u16x8*)p); }

DEV f32x4 MFMA(bf16x8 a, bf16x8 b, f32x4 c) {
  return __builtin_amdgcn_mfma_f32_16x16x32_bf16(a, b, c, 0, 0, 0);
}

// ---- fused routing: count + scan + tile tables + fill + padding init ----
__global__ void k_route(const int* __restrict__ eidx, const float* __restrict__ ew,
                        int* meta, int* slot_token, float* slot_weight, int* pair_slot) {
  __shared__ int cnt[NE], cur[NE], off[NE];
  const int tid = threadIdx.x;           // 1024 threads, 1 block
  if (tid < NE) { cnt[tid] = 0; cur[tid] = 0; }
  __syncthreads();
  for (int p = tid; p < NP; p += 1024) atomicAdd(&cnt[eidx[p] & 7], 1);
  __syncthreads();
  if (tid == 0) {
    int o = 0, t2 = 0, t1 = 0;
    for (int e = 0; e < NE; ++e) {
      off[e] = o; meta[e] = cnt[e]; meta[16 + e] = o;
      const int c = cnt[e];
      o += ((c + 127) >> 7) << 7;
      for (int mt = 0; mt * 256 < c; ++mt) meta[32 + t2++] = e | (mt << 8);
      for (int mt = 0; mt * 128 < c; ++mt) meta[128 + t1++] = e | (mt << 8);
    }
    meta[24] = o; meta[25] = t2; meta[26] = t1;
  }
  __syncthreads();
  for (int s = tid; s < MAXS; s += 1024) slot_token[s] = -1;   // padding default
  __syncthreads();
  for (int p = tid; p < NP; p += 1024) {
    const int e = eidx[p] & 7;
    const int pos = off[e] + atomicAdd(&cur[e], 1);
    slot_token[pos]  = p >> 1;
    slot_weight[pos] = ew[p];
    pair_slot[p] = pos;
  }
}

// ---- merged prep: gather (blocks [0,MAXS)) + weight transpose (rest) ----
__global__ void k_prep(const float* __restrict__ x, const int* __restrict__ slot_token,
                       u16* __restrict__ Xg,
                       const float* __restrict__ w1, const float* __restrict__ w2,
                       const float* __restrict__ w3, u16* __restrict__ w1T,
                       u16* __restrict__ w2T, u16* __restrict__ w3T) {
  __shared__ u16 tile[64][72];
  const int bid = blockIdx.x;
  const int t = threadIdx.x;

  if (bid < MAXS) {
    const int tok = slot_token[bid];
    const int c = t * 4;
    alignas(8) u16 b[4] = {0, 0, 0, 0};
    if (tok >= 0) {
      const float4 v = *reinterpret_cast<const float4*>(x + (size_t)tok * DM + c);
      b[0] = f2bf(v.x); b[1] = f2bf(v.y); b[2] = f2bf(v.z); b[3] = f2bf(v.w);
    }
    *reinterpret_cast<uint2*>(Xg + (size_t)bid * DM + c) = *reinterpret_cast<const uint2*>(b);
    return;
  }

  const int fid = bid - MAXS;
  const int z = fid >> 9;
  const int id = fid & 511;
  const int which = z >> 3, e = z & 7;
  const float* s; u16* d; int K, N, n0, k0;
  const size_t mo = (size_t)e * DM * DF;
  if (which == 0)      { s = w1 + mo; d = w1T + mo; K = DM; N = DF; n0 = (id & 31) * 64; k0 = (id >> 5) * 64; }
  else if (which == 1) { s = w2 + mo; d = w2T + mo; K = DM; N = DF; n0 = (id & 31) * 64; k0 = (id >> 5) * 64; }
  else                 { s = w3 + mo; d = w3T + mo; K = DF; N = DM; n0 = (id & 15) * 64; k0 = (id >> 4) * 64; }

  const int r = t >> 4, cb = (t & 15) * 4;
#pragma unroll
  for (int it = 0; it < 4; ++it) {
    const float4 v = *reinterpret_cast<const float4*>(s + (size_t)(k0 + r + it * 16) * N + n0 + cb);
    tile[r + it * 16][cb + 0] = f2bf(v.x);
    tile[r + it * 16][cb + 1] = f2bf(v.y);
    tile[r + it * 16][cb + 2] = f2bf(v.z);
    tile[r + it * 16][cb + 3] = f2bf(v.w);
  }
  __syncthreads();
  const int nl = t >> 2, ks = (t & 3) * 16;
  alignas(16) u16 vals[16];
#pragma unroll
  for (int j = 0; j < 16; ++j) vals[j] = tile[ks + j][nl];
  u16* dp = d + (size_t)(n0 + nl) * K + k0 + ks;
  *reinterpret_cast<uint4*>(dp)     = *reinterpret_cast<const uint4*>(vals);
  *reinterpret_cast<uint4*>(dp + 8) = *reinterpret_cast<const uint4*>(vals + 8);
}

// ============ GEMM1: H = silu(Xg@w1T) * (Xg@w2T) ============
// BM=256, BN=128 dual, BK=32, 8 waves (2Mx4N), acc 128
// 4 x 32KB LDS buffers, prefetch 3 tiles ahead, vmcnt(12) (never drains)
// stride-64B rows: linear layout is bank-conflict-free (2-way max) for both sides
__global__ __launch_bounds__(512, 2)
void k_gemm1(const u16* __restrict__ Xg, const u16* __restrict__ w1T, const u16* __restrict__ w2T,
             u16* __restrict__ H, const int* __restrict__ meta) {
  const int bid = blockIdx.x;
  const int xcd = bid & 7;
  const int local = bid >> 3;              // 0..141
  const int ti = local >> 1;
  if (ti >= meta[25]) return;
  const int n0 = (xcd * 2 + (local & 1)) * 128;
  const int ent = meta[32 + ti];
  const int e = ent & 255, mt = ent >> 8;
  const int base = meta[16 + e];
  const int cntp = meta[17 + e] - base;

  // per buffer (32KB): A[256][64B] @0 (16KB) | B1[128][64B] @16384 | B2 @24576
  __shared__ __align__(16) char sm[4][32768];

  const int tid = threadIdx.x;
  const int lane = tid & 63;
  const int w = tid >> 6;
  const int wr = w >> 2, wc = w & 3;       // 2M x 4N
  const int lrow = lane & 15, lk = lane >> 4;
  const int Abase  = (wr * 128 + lrow) * 64 + lk * 16;
  const int B1base = 16384 + (wc * 32 + lrow) * 64 + lk * 16;
  const int B2base = B1base + 8192;

  // staging: thread t -> row t>>2, 16B slot t&3 (linear dest, linear src)
  const char* AgT = (const char*)(Xg + (size_t)(base + mt * 256) * DM) + (size_t)(tid >> 2) * 2048 + (tid & 3) * 16;
  const char* B1T = (const char*)(w1T + ((size_t)e * DF + n0) * DM)    + (size_t)(tid >> 2) * 2048 + (tid & 3) * 16;
  const char* B2T = (const char*)(w2T + ((size_t)e * DF + n0) * DM)    + (size_t)(tid >> 2) * 2048 + (tid & 3) * 16;

  f32x4 acc1[8][2] = {};
  f32x4 acc2[8][2] = {};

  auto STAGE = [&](char* d, int kt) {      // 4 gload16/thread: one BK=32 tile
    const size_t kb = (size_t)kt * 64;
    gload16(AgT + kb,          d + tid * 16);            // A rows 0..127
    gload16(AgT + 262144 + kb, d + 8192 + tid * 16);     // A rows 128..255
    gload16(B1T + kb,          d + 16384 + tid * 16);    // B1 rows 0..127
    gload16(B2T + kb,          d + 24576 + tid * 16);    // B2 rows 0..127
  };

  auto MF16 = [&](int mbase, const bf16x8* a, const bf16x8* b1f, const bf16x8* b2f) {
    __builtin_amdgcn_s_setprio(1);
#pragma unroll
    for (int j = 0; j < 4; ++j)
#pragma unroll
      for (int n = 0; n < 2; ++n) {
        acc1[mbase + j][n] = MFMA(a[j], b1f[n], acc1[mbase + j][n]);
        acc2[mbase + j][n] = MFMA(a[j], b2f[n], acc2[mbase + j][n]);
      }
    __builtin_amdgcn_s_setprio(0);
  };

  STAGE(sm[0], 0); STAGE(sm[1], 1); STAGE(sm[2], 2);     // 3-deep prologue

  for (int kt = 0; kt < 32; ++kt) {
    const char* s = sm[kt & 3];
    char* d = sm[(kt + 3) & 3];
    const int kbn = (kt + 3 < 32) ? kt + 3 : 31;         // dummy refill at tail

    STAGE(d, kbn);                                       // tile t+3: 4 loads
    asm volatile("s_waitcnt vmcnt(12)" ::: "memory");    // tile t landed; 3 tiles in flight
    __builtin_amdgcn_s_barrier();

    bf16x8 b1f[2], b2f[2], a[4];
#pragma unroll
    for (int n = 0; n < 2; ++n) {
      b1f[n] = ldfrag(s + B1base + n * 1024);            // 16 rows * 64B
      b2f[n] = ldfrag(s + B2base + n * 1024);
    }
#pragma unroll
    for (int j = 0; j < 4; ++j)
      a[j] = ldfrag(s + Abase + j * 1024);
    MF16(0, a, b1f, b2f);
#pragma unroll
    for (int j = 0; j < 4; ++j)
      a[j] = ldfrag(s + Abase + (4 + j) * 1024);
    MF16(4, a, b1f, b2f);
    __builtin_amdgcn_s_barrier();                        // all done with buf before restage
  }

  u16* Hrow = H + (size_t)(base + mt * 256) * DF + n0;
#pragma unroll
  for (int m = 0; m < 8; ++m)
#pragma unroll
    for (int r = 0; r < 4; ++r) {
      const int rloc = wr * 128 + m * 16 + lk * 4 + r;
      if (mt * 256 + rloc >= cntp) continue;
      u16* hp = Hrow + (size_t)rloc * DF + wc * 32 + lrow;
#pragma unroll
      for (int n = 0; n < 2; ++n) {
        const float h1 = acc1[m][n][r], h2 = acc2[m][n][r];
        const float sv = h1 / (1.f + __expf(-h1)) * h2;   // silu(h1)*h2
        hp[n * 16] = f2bf(sv);
      }
    }
}

// ============ GEMM2 (R13 verbatim): O_slot = wgt * (H @ w3T) ============
__global__ __launch_bounds__(256, 2)
void k_gemm2(const u16* __restrict__ H, const u16* __restrict__ w3T, const int* __restrict__ meta,
             const float* __restrict__ slot_weight, u16* __restrict__ O) {
  const int bid = blockIdx.x;
  const int ti = bid >> 3;
  if (ti >= meta[26]) return;
  const int n0 = (bid & 7) * 128;
  const int ent = meta[128 + ti];
  const int e = ent & 255, mt = ent >> 8;
  const int base = meta[16 + e];

  __shared__ __align__(16) char sm[2][32768];

  const int tid = threadIdx.x;
  const int lane = tid & 63;
  const int w = tid >> 6;                  // 0..3
  const int wr = w >> 1, wc = w & 1;       // 2M x 2N
  const int lrow = lane & 15, lk = lane >> 4;
  const int SX = lrow & 7;
  int cofs[2];
  cofs[0] = ((0 * 4 + lk) ^ SX) * 16;
  cofs[1] = ((1 * 4 + lk) ^ SX) * 16;
  const int Abase = (wr * 64 + lrow) * 128;
  const int Bbase = 16384 + (wc * 64 + lrow) * 128;

  const int srow = tid >> 3;               // 0..31
  const int scolw = ((tid & 7) ^ (srow & 7)) * 16;

  const char* AgT = (const char*)(H + (size_t)(base + mt * 128) * DF) + (size_t)srow * 4096 + scolw;
  const char* BgT = (const char*)(w3T + ((size_t)e * DM + n0) * DF)   + (size_t)srow * 4096 + scolw;

  f32x4 acc[4][4] = {};

  auto SPA = [&](char* d, size_t kb) {
#pragma unroll
    for (int c = 0; c < 4; ++c)
      gload16(AgT + (size_t)c * 131072 + kb, d + c * 4096 + tid * 16);
  };
  auto SPB = [&](char* d, size_t kb) {
#pragma unroll
    for (int c = 0; c < 4; ++c)
      gload16(BgT + (size_t)c * 131072 + kb, d + 16384 + c * 4096 + tid * 16);
  };

  bf16x8 bf[4][2];

  auto LDA4 = [&](const char* s, int ks, bf16x8* a) {
#pragma unroll
    for (int j = 0; j < 4; ++j)
      a[j] = ldfrag(s + Abase + j * 2048 + cofs[ks]);
  };
  auto MF16 = [&](int ks, const bf16x8* a) {
    __builtin_amdgcn_s_setprio(1);
#pragma unroll
    for (int j = 0; j < 4; ++j)
#pragma unroll
      for (int n = 0; n < 4; ++n)
        acc[j][n] = MFMA(a[j], bf[n][ks], acc[j][n]);
    __builtin_amdgcn_s_setprio(0);
  };

  SPA(sm[0], 0); SPB(sm[0], 0);

  for (int kt = 0; kt < 32; ++kt) {
    const char* s = sm[kt & 1];
    char* d = sm[(kt + 1) & 1];
    const size_t kbn = (size_t)((kt + 1 < 32) ? kt + 1 : 31) * 128;
    bf16x8 a[4];

    SPA(d, kbn);
    asm volatile("s_waitcnt vmcnt(4)" ::: "memory");
    __builtin_amdgcn_s_barrier();
#pragma unroll
    for (int n = 0; n < 4; ++n)
#pragma unroll
      for (int s2 = 0; s2 < 2; ++s2)
        bf[n][s2] = ldfrag(s + Bbase + n * 2048 + cofs[s2]);
    LDA4(s, 0, a);
    MF16(0, a);
    __builtin_amdgcn_s_barrier();

    LDA4(s, 1, a);
    SPB(d, kbn);
    __builtin_amdgcn_s_barrier();
    MF16(1, a);
    __builtin_amdgcn_s_barrier();
  }

  const int sb = base + mt * 128;
#pragma unroll
  for (int m = 0; m < 4; ++m)
#pragma unroll
    for (int r = 0; r < 4; ++r) {
      const int rloc = wr * 64 + m * 16 + lk * 4 + r;
      const float wgt = slot_weight[sb + rloc];
      u16* op = O + (size_t)(sb + rloc) * DM + n0 + wc * 64 + lrow;
#pragma unroll
      for (int n = 0; n < 4; ++n)
        op[n * 16] = f2bf(wgt * acc[m][n][r]);
    }
}

// out[t] = O[slot(2t)] + O[slot(2t+1)]   -- 8 elems/thread, 2 tokens/block
__global__ void k_combine(const u16* __restrict__ O, const int* __restrict__ pair_slot,
                          float* __restrict__ out) {
  const int tok = blockIdx.x * 2 + (threadIdx.x >> 7);
  const int c = (threadIdx.x & 127) * 8;
  const int sa = pair_slot[2 * tok], sb = pair_slot[2 * tok + 1];
  const uint4 va = *reinterpret_cast<const uint4*>(O + (size_t)sa * DM + c);
  const uint4 vb = *reinterpret_cast<const uint4*>(O + (size_t)sb * DM + c);
  float4 r0, r1;
  r0.x = bflo(va.x) + bflo(vb.x);  r0.y = bfhi(va.x) + bfhi(vb.x);
  r0.z = bflo(va.y) + bflo(vb.y);  r0.w = bfhi(va.y) + bfhi(vb.y);
  r1.x = bflo(va.z) + bflo(vb.z);  r1.y = bfhi(va.z) + bfhi(vb.z);
  r1.z = bflo(va.w) + bflo(vb.w);  r1.w = bfhi(va.w) + bfhi(vb.w);
  float* op = out + (size_t)tok * DM + c;
  *reinterpret_cast<float4*>(op)     = r0;
  *reinterpret_cast<float4*>(op + 4) = r1;
}

extern "C" void kernel_launch(void* const* d_in, const int* in_sizes, int n_in,
                              void* d_out, int out_size, void* d_ws, size_t ws_size,
                              hipStream_t stream) {
  const float* x  = (const float*)d_in[0];
  const int* eidx = (const int*)d_in[1];
  const float* ew = (const float*)d_in[2];
  const float* w1 = (const float*)d_in[3];
  const float* w2 = (const float*)d_in[4];
  const float* w3 = (const float*)d_in[5];
  float* out = (float*)d_out;
  char* ws = (char*)d_ws;

  int* meta          = (int*)ws;                           // 2 KB (both tables)
  int* pair_slot     = (int*)(ws + 2048);                  // 64 KB
  int* slot_token    = (int*)(ws + 2048 + 65536);
  float* slot_weight = (float*)(ws + 2048 + 65536 + (size_t)MAXS * 4);
  size_t off = 2048 + 65536 + (size_t)MAXS * 8;
  u16* Xg  = (u16*)(ws + off); off += (size_t)MAXS * DM * 2;   // reused as O_slot
  u16* w1T = (u16*)(ws + off); off += (size_t)NE * DM * DF * 2;
  u16* w2T = (u16*)(ws + off); off += (size_t)NE * DM * DF * 2;
  u16* w3T = (u16*)(ws + off); off += (size_t)NE * DM * DF * 2;
  u16* H   = (u16*)(ws + off);  // MAXS * DF * 2 bytes
  u16* O   = Xg;                // Xg is dead after k_gemm1

  k_route<<<1, 1024, 0, stream>>>(eidx, ew, meta, slot_token, slot_weight, pair_slot);
  k_prep<<<NPREP, 256, 0, stream>>>(x, slot_token, Xg, w1, w2, w3, w1T, w2T, w3T);
  k_gemm1<<<NWG1, 512, 0, stream>>>(Xg, w1T, w2T, H, meta);
  k_gemm2<<<NWG2, 256, 0, stream>>>(H, w3T, meta, slot_weight, O);
  k_combine<<<NT / 2, 256, 0, stream>>>(O, pair_slot, out);
}

// Round 18
// 372.958 us; speedup vs baseline: 1.0726x; 1.0726x over previous
//
#include <hip/hip_runtime.h>
#include <cstdint>

typedef unsigned short u16;
typedef u16 u16x8 __attribute__((ext_vector_type(8)));
typedef __bf16 bf16x8 __attribute__((ext_vector_type(8)));
typedef float f32x4 __attribute__((ext_vector_type(4)));

#define DEV static __device__ __forceinline__

// problem constants
constexpr int NT = 8192;         // tokens
constexpr int NP = NT * 2;       // 16384 (token, k) pairs
constexpr int NE = 8;
constexpr int DM = 1024;
constexpr int DF = 2048;
constexpr int MAXS = 17664;      // 16384 + 8*127 pad + 256-tile overhang
constexpr int MAXT128 = 136;
constexpr int NWG1 = 8 * 142;    // 1136: xcd n-major mapping (R11 best)
constexpr int NWG2 = 8 * MAXT128;// 1088
constexpr int NTRANS = 24 * 512; // transpose sub-grid (flattened)
constexpr int NPREP = MAXS + NTRANS;

DEV u16 f2bf(float f) {          // RTNE float -> bf16 bits
  uint32_t u = __builtin_bit_cast(uint32_t, f);
  u += 0x7fffu + ((u >> 16) & 1u);
  return (u16)(u >> 16);
}

DEV float bflo(uint32_t u) { return __builtin_bit_cast(float, u << 16); }
DEV float bfhi(uint32_t u) { return __builtin_bit_cast(float, u & 0xffff0000u); }

DEV void gload16(const void* g, void* l) {
  __builtin_amdgcn_global_load_lds((const __attribute__((address_space(1))) void*)g,
                                   (__attribute__((address_space(3))) void*)l, 16, 0, 0);
}

DEV bf16x8 ldfrag(const char* p) { return __builtin_bit_cast(bf16x8, *(const u16x8*)p); }

DEV f32x4 MFMA(bf16x8 a, bf16x8 b, f32x4 c) {
  return __builtin_amdgcn_mfma_f32_16x16x32_bf16(a, b, c, 0, 0, 0);
}

// ---- fused routing: count + scan + tile tables + fill + padding init ----
__global__ void k_route(const int* __restrict__ eidx, const float* __restrict__ ew,
                        int* meta, int* slot_token, float* slot_weight, int* pair_slot) {
  __shared__ int cnt[NE], cur[NE], off[NE];
  const int tid = threadIdx.x;           // 1024 threads, 1 block
  if (tid < NE) { cnt[tid] = 0; cur[tid] = 0; }
  __syncthreads();
  for (int p = tid; p < NP; p += 1024) atomicAdd(&cnt[eidx[p] & 7], 1);
  __syncthreads();
  if (tid == 0) {
    int o = 0, t2 = 0, t1 = 0;
    for (int e = 0; e < NE; ++e) {
      off[e] = o; meta[e] = cnt[e]; meta[16 + e] = o;
      const int c = cnt[e];
      o += ((c + 127) >> 7) << 7;
      for (int mt = 0; mt * 256 < c; ++mt) meta[32 + t2++] = e | (mt << 8);
      for (int mt = 0; mt * 128 < c; ++mt) meta[128 + t1++] = e | (mt << 8);
    }
    meta[24] = o; meta[25] = t2; meta[26] = t1;
  }
  __syncthreads();
  for (int s = tid; s < MAXS; s += 1024) slot_token[s] = -1;   // padding default
  __syncthreads();
  for (int p = tid; p < NP; p += 1024) {
    const int e = eidx[p] & 7;
    const int pos = off[e] + atomicAdd(&cur[e], 1);
    slot_token[pos]  = p >> 1;
    slot_weight[pos] = ew[p];
    pair_slot[p] = pos;
  }
}

// ---- merged prep: gather (blocks [0,MAXS)) + weight transpose (rest) ----
__global__ void k_prep(const float* __restrict__ x, const int* __restrict__ slot_token,
                       u16* __restrict__ Xg,
                       const float* __restrict__ w1, const float* __restrict__ w2,
                       const float* __restrict__ w3, u16* __restrict__ w1T,
                       u16* __restrict__ w2T, u16* __restrict__ w3T) {
  __shared__ u16 tile[64][72];
  const int bid = blockIdx.x;
  const int t = threadIdx.x;

  if (bid < MAXS) {
    const int tok = slot_token[bid];
    const int c = t * 4;
    alignas(8) u16 b[4] = {0, 0, 0, 0};
    if (tok >= 0) {
      const float4 v = *reinterpret_cast<const float4*>(x + (size_t)tok * DM + c);
      b[0] = f2bf(v.x); b[1] = f2bf(v.y); b[2] = f2bf(v.z); b[3] = f2bf(v.w);
    }
    *reinterpret_cast<uint2*>(Xg + (size_t)bid * DM + c) = *reinterpret_cast<const uint2*>(b);
    return;
  }

  const int fid = bid - MAXS;
  const int z = fid >> 9;
  const int id = fid & 511;
  const int which = z >> 3, e = z & 7;
  const float* s; u16* d; int K, N, n0, k0;
  const size_t mo = (size_t)e * DM * DF;
  if (which == 0)      { s = w1 + mo; d = w1T + mo; K = DM; N = DF; n0 = (id & 31) * 64; k0 = (id >> 5) * 64; }
  else if (which == 1) { s = w2 + mo; d = w2T + mo; K = DM; N = DF; n0 = (id & 31) * 64; k0 = (id >> 5) * 64; }
  else                 { s = w3 + mo; d = w3T + mo; K = DF; N = DM; n0 = (id & 15) * 64; k0 = (id >> 4) * 64; }

  const int r = t >> 4, cb = (t & 15) * 4;
#pragma unroll
  for (int it = 0; it < 4; ++it) {
    const float4 v = *reinterpret_cast<const float4*>(s + (size_t)(k0 + r + it * 16) * N + n0 + cb);
    tile[r + it * 16][cb + 0] = f2bf(v.x);
    tile[r + it * 16][cb + 1] = f2bf(v.y);
    tile[r + it * 16][cb + 2] = f2bf(v.z);
    tile[r + it * 16][cb + 3] = f2bf(v.w);
  }
  __syncthreads();
  const int nl = t >> 2, ks = (t & 3) * 16;
  alignas(16) u16 vals[16];
#pragma unroll
  for (int j = 0; j < 16; ++j) vals[j] = tile[ks + j][nl];
  u16* dp = d + (size_t)(n0 + nl) * K + k0 + ks;
  *reinterpret_cast<uint4*>(dp)     = *reinterpret_cast<const uint4*>(vals);
  *reinterpret_cast<uint4*>(dp + 8) = *reinterpret_cast<const uint4*>(vals + 8);
}

// ============ GEMM1 (R11 verbatim): H = silu(Xg@w1T) * (Xg@w2T) ============
__global__ __launch_bounds__(512, 2)
void k_gemm1(const u16* __restrict__ Xg, const u16* __restrict__ w1T, const u16* __restrict__ w2T,
             u16* __restrict__ H, const int* __restrict__ meta) {
  const int bid = blockIdx.x;
  const int xcd = bid & 7;
  const int local = bid >> 3;              // 0..141
  const int ti = local >> 1;
  if (ti >= meta[25]) return;
  const int n0 = (xcd * 2 + (local & 1)) * 128;
  const int ent = meta[32 + ti];
  const int e = ent & 255, mt = ent >> 8;
  const int base = meta[16 + e];
  const int cntp = meta[17 + e] - base;

  __shared__ __align__(16) char sm[2][65536];

  const int tid = threadIdx.x;
  const int lane = tid & 63;
  const int w = tid >> 6;
  const int wr = w >> 2, wc = w & 3;       // 2M x 4N
  const int lrow = lane & 15, lk = lane >> 4;
  const int SX = lrow & 7;
  int cofs[2];
  cofs[0] = ((0 * 4 + lk) ^ SX) * 16;
  cofs[1] = ((1 * 4 + lk) ^ SX) * 16;
  const int Abase  = (wr * 128 + lrow) * 128;
  const int B1base = 32768 + (wc * 32 + lrow) * 128;
  const int B2base = B1base + 16384;

  const int srow8 = tid >> 3;
  const int scolw = ((tid & 7) ^ (srow8 & 7)) * 16;

  const char* AgT = (const char*)(Xg + (size_t)(base + mt * 256) * DM) + (size_t)srow8 * 2048 + scolw;
  const char* B1T = (const char*)(w1T + ((size_t)e * DF + n0) * DM)    + (size_t)srow8 * 2048 + scolw;
  const char* B2T = (const char*)(w2T + ((size_t)e * DF + n0) * DM)    + (size_t)srow8 * 2048 + scolw;

  f32x4 acc1[8][2] = {};
  f32x4 acc2[8][2] = {};

  auto SP = [&](char* d, size_t kb, int q) {
    switch (q) {
      case 0: gload16(AgT + kb,          d + tid * 16);
              gload16(AgT + 131072 + kb, d + 8192  + tid * 16); break;
      case 1: gload16(AgT + 262144 + kb, d + 16384 + tid * 16);
              gload16(AgT + 393216 + kb, d + 24576 + tid * 16); break;
      case 2: gload16(B1T + kb,          d + 32768 + tid * 16);
              gload16(B1T + 131072 + kb, d + 40960 + tid * 16); break;
      case 3: gload16(B2T + kb,          d + 49152 + tid * 16);
              gload16(B2T + 131072 + kb, d + 57344 + tid * 16); break;
    }
  };

  bf16x8 b1f[2][2], b2f[2][2];

  auto LDA4 = [&](const char* s, int mh, int ks, bf16x8* a) {
#pragma unroll
    for (int j = 0; j < 4; ++j)
      a[j] = ldfrag(s + Abase + mh * 8192 + j * 2048 + cofs[ks]);
  };
  auto MF16 = [&](int mh, int ks, const bf16x8* a) {
    __builtin_amdgcn_s_setprio(1);
#pragma unroll
    for (int j = 0; j < 4; ++j)
#pragma unroll
      for (int n = 0; n < 2; ++n) {
        acc1[mh * 4 + j][n] = MFMA(a[j], b1f[n][ks], acc1[mh * 4 + j][n]);
        acc2[mh * 4 + j][n] = MFMA(a[j], b2f[n][ks], acc2[mh * 4 + j][n]);
      }
    __builtin_amdgcn_s_setprio(0);
  };

  SP(sm[0], 0, 0); SP(sm[0], 0, 1); SP(sm[0], 0, 2); SP(sm[0], 0, 3);

  for (int kt = 0; kt < 16; ++kt) {
    const char* s = sm[kt & 1];
    char* d = sm[(kt + 1) & 1];
    const size_t kbn = (size_t)((kt + 1 < 16) ? kt + 1 : 15) * 128;
    bf16x8 a[4];

    SP(d, kbn, 0);
    asm volatile("s_waitcnt vmcnt(2)" ::: "memory");
    __builtin_amdgcn_s_barrier();
#pragma unroll
    for (int n = 0; n < 2; ++n)
#pragma unroll
      for (int s2 = 0; s2 < 2; ++s2) {
        b1f[n][s2] = ldfrag(s + B1base + n * 2048 + cofs[s2]);
        b2f[n][s2] = ldfrag(s + B2base + n * 2048 + cofs[s2]);
      }
    LDA4(s, 0, 0, a);
    MF16(0, 0, a);
    __builtin_amdgcn_s_barrier();

    LDA4(s, 1, 0, a);
    SP(d, kbn, 1);
    __builtin_amdgcn_s_barrier();
    MF16(1, 0, a);
    __builtin_amdgcn_s_barrier();

    LDA4(s, 0, 1, a);
    SP(d, kbn, 2);
    __builtin_amdgcn_s_barrier();
    MF16(0, 1, a);
    __builtin_amdgcn_s_barrier();

    LDA4(s, 1, 1, a);
    SP(d, kbn, 3);
    __builtin_amdgcn_s_barrier();
    MF16(1, 1, a);
    __builtin_amdgcn_s_barrier();
  }

  u16* Hrow = H + (size_t)(base + mt * 256) * DF + n0;
#pragma unroll
  for (int m = 0; m < 8; ++m)
#pragma unroll
    for (int r = 0; r < 4; ++r) {
      const int rloc = wr * 128 + m * 16 + lk * 4 + r;
      if (mt * 256 + rloc >= cntp) continue;
      u16* hp = Hrow + (size_t)rloc * DF + wc * 32 + lrow;
#pragma unroll
      for (int n = 0; n < 2; ++n) {
        const float h1 = acc1[m][n][r], h2 = acc2[m][n][r];
        const float sv = h1 / (1.f + __expf(-h1)) * h2;   // silu(h1)*h2
        hp[n * 16] = f2bf(sv);
      }
    }
}

// ============ GEMM2 (R13 verbatim): O_slot = wgt * (H @ w3T) ============
__global__ __launch_bounds__(256, 2)
void k_gemm2(const u16* __restrict__ H, const u16* __restrict__ w3T, const int* __restrict__ meta,
             const float* __restrict__ slot_weight, u16* __restrict__ O) {
  const int bid = blockIdx.x;
  const int ti = bid >> 3;
  if (ti >= meta[26]) return;
  const int n0 = (bid & 7) * 128;
  const int ent = meta[128 + ti];
  const int e = ent & 255, mt = ent >> 8;
  const int base = meta[16 + e];

  __shared__ __align__(16) char sm[2][32768];

  const int tid = threadIdx.x;
  const int lane = tid & 63;
  const int w = tid >> 6;                  // 0..3
  const int wr = w >> 1, wc = w & 1;       // 2M x 2N
  const int lrow = lane & 15, lk = lane >> 4;
  const int SX = lrow & 7;
  int cofs[2];
  cofs[0] = ((0 * 4 + lk) ^ SX) * 16;
  cofs[1] = ((1 * 4 + lk) ^ SX) * 16;
  const int Abase = (wr * 64 + lrow) * 128;
  const int Bbase = 16384 + (wc * 64 + lrow) * 128;

  const int srow = tid >> 3;               // 0..31
  const int scolw = ((tid & 7) ^ (srow & 7)) * 16;

  const char* AgT = (const char*)(H + (size_t)(base + mt * 128) * DF) + (size_t)srow * 4096 + scolw;
  const char* BgT = (const char*)(w3T + ((size_t)e * DM + n0) * DF)   + (size_t)srow * 4096 + scolw;

  f32x4 acc[4][4] = {};

  auto SPA = [&](char* d, size_t kb) {
#pragma unroll
    for (int c = 0; c < 4; ++c)
      gload16(AgT + (size_t)c * 131072 + kb, d + c * 4096 + tid * 16);
  };
  auto SPB = [&](char* d, size_t kb) {
#pragma unroll
    for (int c = 0; c < 4; ++c)
      gload16(BgT + (size_t)c * 131072 + kb, d + 16384 + c * 4096 + tid * 16);
  };

  bf16x8 bf[4][2];

  auto LDA4 = [&](const char* s, int ks, bf16x8* a) {
#pragma unroll
    for (int j = 0; j < 4; ++j)
      a[j] = ldfrag(s + Abase + j * 2048 + cofs[ks]);
  };
  auto MF16 = [&](int ks, const bf16x8* a) {
    __builtin_amdgcn_s_setprio(1);
#pragma unroll
    for (int j = 0; j < 4; ++j)
#pragma unroll
      for (int n = 0; n < 4; ++n)
        acc[j][n] = MFMA(a[j], bf[n][ks], acc[j][n]);
    __builtin_amdgcn_s_setprio(0);
  };

  SPA(sm[0], 0); SPB(sm[0], 0);

  for (int kt = 0; kt < 32; ++kt) {
    const char* s = sm[kt & 1];
    char* d = sm[(kt + 1) & 1];
    const size_t kbn = (size_t)((kt + 1 < 32) ? kt + 1 : 31) * 128;
    bf16x8 a[4];

    SPA(d, kbn);
    asm volatile("s_waitcnt vmcnt(4)" ::: "memory");
    __builtin_amdgcn_s_barrier();
#pragma unroll
    for (int n = 0; n < 4; ++n)
#pragma unroll
      for (int s2 = 0; s2 < 2; ++s2)
        bf[n][s2] = ldfrag(s + Bbase + n * 2048 + cofs[s2]);
    LDA4(s, 0, a);
    MF16(0, a);
    __builtin_amdgcn_s_barrier();

    LDA4(s, 1, a);
    SPB(d, kbn);
    __builtin_amdgcn_s_barrier();
    MF16(1, a);
    __builtin_amdgcn_s_barrier();
  }

  const int sb = base + mt * 128;
#pragma unroll
  for (int m = 0; m < 4; ++m)
#pragma unroll
    for (int r = 0; r < 4; ++r) {
      const int rloc = wr * 64 + m * 16 + lk * 4 + r;
      const float wgt = slot_weight[sb + rloc];
      u16* op = O + (size_t)(sb + rloc) * DM + n0 + wc * 64 + lrow;
#pragma unroll
      for (int n = 0; n < 4; ++n)
        op[n * 16] = f2bf(wgt * acc[m][n][r]);
    }
}

// out[t] = O[slot(2t)] + O[slot(2t+1)]
__global__ void k_combine(const u16* __restrict__ O, const int* __restrict__ pair_slot,
                          float* __restrict__ out) {
  const int t = blockIdx.x;
  const int c = threadIdx.x * 4;
  const int sa = pair_slot[2 * t], sb = pair_slot[2 * t + 1];
  const uint2 va = *reinterpret_cast<const uint2*>(O + (size_t)sa * DM + c);
  const uint2 vb = *reinterpret_cast<const uint2*>(O + (size_t)sb * DM + c);
  float4 r;
  r.x = bflo(va.x) + bflo(vb.x);
  r.y = bfhi(va.x) + bfhi(vb.x);
  r.z = bflo(va.y) + bflo(vb.y);
  r.w = bfhi(va.y) + bfhi(vb.y);
  *reinterpret_cast<float4*>(out + (size_t)t * DM + c) = r;
}

extern "C" void kernel_launch(void* const* d_in, const int* in_sizes, int n_in,
                              void* d_out, int out_size, void* d_ws, size_t ws_size,
                              hipStream_t stream) {
  const float* x  = (const float*)d_in[0];
  const int* eidx = (const int*)d_in[1];
  const float* ew = (const float*)d_in[2];
  const float* w1 = (const float*)d_in[3];
  const float* w2 = (const float*)d_in[4];
  const float* w3 = (const float*)d_in[5];
  float* out = (float*)d_out;
  char* ws = (char*)d_ws;

  int* meta          = (int*)ws;                           // 2 KB (both tables)
  int* pair_slot     = (int*)(ws + 2048);                  // 64 KB
  int* slot_token    = (int*)(ws + 2048 + 65536);
  float* slot_weight = (float*)(ws + 2048 + 65536 + (size_t)MAXS * 4);
  size_t off = 2048 + 65536 + (size_t)MAXS * 8;
  u16* Xg  = (u16*)(ws + off); off += (size_t)MAXS * DM * 2;   // reused as O_slot
  u16* w1T = (u16*)(ws + off); off += (size_t)NE * DM * DF * 2;
  u16* w2T = (u16*)(ws + off); off += (size_t)NE * DM * DF * 2;
  u16* w3T = (u16*)(ws + off); off += (size_t)NE * DM * DF * 2;
  u16* H   = (u16*)(ws + off);  // MAXS * DF * 2 bytes
  u16* O   = Xg;                // Xg is dead after k_gemm1

  k_route<<<1, 1024, 0, stream>>>(eidx, ew, meta, slot_token, slot_weight, pair_slot);
  k_prep<<<NPREP, 256, 0, stream>>>(x, slot_token, Xg, w1, w2, w3, w1T, w2T, w3T);
  k_gemm1<<<NWG1, 512, 0, stream>>>(Xg, w1T, w2T, H, meta);
  k_gemm2<<<NWG2, 256, 0, stream>>>(H, w3T, meta, slot_weight, O);
  k_combine<<<NT, 256, 0, stream>>>(O, pair_slot, out);
}